// Round 8
// baseline (2354.172 us; speedup 1.0000x reference)
//
#include <hip/hip_runtime.h>

// TDT loss, fixed shapes from setup_inputs():
#define TDT_B  8
#define TDT_T  256
#define TDT_U  64
#define TDT_U1 65
#define TDT_V1 513   // V+1, blank index = 512
#define TP     275   // 4 zero-pad slices + 256 + FIFO slack
#define SIG    0.05f
#define SHIFT  3.0f  // exponent shift PER TIME-STEP: duration-d weight carries SHIFT*d

// ws layout (floats):
//   WB: float4[B][TP][U1] = exp(lpb + ld_i - SIG + SHIFT*(i+1))
//   WY: float4[B][TP][U]  = exp(lpy + ld_i - SIG + SHIFT*(i+1))
//   GC: float4[B][TP]     = WB[b][tp][u=64] (compact copy for the DP's G column)
//   CNT: unsigned[256]    = per-t-slice completion counters (520 rows each)
#define OFF_PYD 572000                        // 8*275*65*4
#define OFF_GC  1135200                       // + 8*275*64*4
#define OFF_CNT 1144000                       // + 8*275*4
#define ROWS_PER_SLICE 520u                   // 8 b * 65 u

// Zero the slice counters + out (ws is poisoned once, never re-poisoned).
__global__ __launch_bounds__(256) void k_zero(float* __restrict__ out,
                                              unsigned* __restrict__ cnt) {
  cnt[threadIdx.x] = 0u;
  if (threadIdx.x == 0) out[0] = 0.f;
}

// DPP wave_shr:1 (ctrl 0x138), bound_ctrl=1 -> lane 0 reads 0. VALU-pipe
// lane shift replacing ds_bpermute on the serial t-chain.
__device__ __forceinline__ float shup1(float x) {
  const int r = __builtin_amdgcn_update_dpp(
      0, __float_as_int(x), 0x138, 0xf, 0xf, true);
  return __int_as_float(r);
}

// Fused kernel. Blocks 0..7: DP consumers (one wave, b = blockIdx).
// Blocks 8+: producers; 4 waves/block, one (b,t,u) row per wave, rows in
// t-MAJOR order so the production frontier advances with dispatch order.
// Producer publishes each row with a release atomicAdd on cnt[t]; consumer
// acquire-polls cnt so cross-XCD stores are visible (guide G16).
__global__ __launch_bounds__(256, 2) void k_fused(
    const float* __restrict__ la, const float* __restrict__ da,
    const int* __restrict__ tgt, float* __restrict__ ws,
    float* __restrict__ out)
{
  unsigned* cnt = (unsigned*)(ws + OFF_CNT);

  if (blockIdx.x >= 8) {
    // ---------------- producer: one row per wave, t-major order ----------
    const int l   = threadIdx.x & 63;
    const int idx = (blockIdx.x - 8) * 4 + (threadIdx.x >> 6); // [0, 133120)
    const int t   = idx / 520;
    const int rem = idx - t * 520;
    const int b   = rem / 65;
    const int u   = rem - b * 65;
    const int r   = (b * TDT_T + t) * TDT_U1 + u;   // row in label_acts

    const float* row = la + (size_t)r * TDT_V1;
    const int ofs = r & 1;                  // odd rows: shift by 1 for 8B align
    const float2* p2 = (const float2*)(row + ofs);
    float2 w[4];
#pragma unroll
    for (int k = 0; k < 4; ++k) w[k] = p2[l + (k << 6)];
    const float extra = row[ofs ? 0 : 512];

    float m = extra;
#pragma unroll
    for (int k = 0; k < 4; ++k) m = fmaxf(m, fmaxf(w[k].x, w[k].y));
#pragma unroll
    for (int off = 32; off; off >>= 1) m = fmaxf(m, __shfl_xor(m, off));
    float s = (l == 0) ? __expf(extra - m) : 0.f;
#pragma unroll
    for (int k = 0; k < 4; ++k) s += __expf(w[k].x - m) + __expf(w[k].y - m);
#pragma unroll
    for (int off = 32; off; off >>= 1) s += __shfl_xor(s, off);
    const float lse = m + __logf(s);

    const float4 dv = *(const float4*)(da + ((size_t)r << 2));
    const float m4 = fmaxf(fmaxf(dv.x, dv.y), fmaxf(dv.z, dv.w));
    const float l4 = m4 + __logf(__expf(dv.x - m4) + __expf(dv.y - m4) +
                                 __expf(dv.z - m4) + __expf(dv.w - m4));
    const float d0 = dv.x - l4 + SHIFT * 1.0f;
    const float d1 = dv.y - l4 + SHIFT * 2.0f;
    const float d2 = dv.z - l4 + SHIFT * 3.0f;
    const float d3 = dv.w - l4 + SHIFT * 4.0f;

    // blank logit (elem 512) -> lane 0
    const float xb_lane = ofs ? w[3].y : extra;
    const float xb = __shfl(xb_lane, ofs ? 63 : 0);

    // target logit -> lane 0 (owner lane computed uniformly)
    const int tg = (u < TDT_U) ? tgt[b * TDT_U + u] : -1;
    float vt = 0.f;
#pragma unroll
    for (int k = 0; k < 4; ++k) {
      const int base = ofs + ((l + (k << 6)) << 1);
      if (base == tg)     vt = w[k].x;
      if (base + 1 == tg) vt = w[k].y;
    }
    if (ofs && tg == 0 && l == 0) vt = extra;
    const int owl = (ofs && tg == 0) ? 0 : (((tg - ofs) >> 1) & 63);
    const float vt0 = __shfl(vt, owl);

    if (l == 0) {
      float4* WB4 = (float4*)ws;
      float4* WY4 = (float4*)(ws + OFF_PYD);
      float4* GC4 = (float4*)(ws + OFF_GC);
      const int tp = t + 4;

      const float pb = xb - lse - SIG;
      const float4 wb = make_float4(__expf(pb + d0), __expf(pb + d1),
                                    __expf(pb + d2), __expf(pb + d3));
      WB4[(b * TP + tp) * TDT_U1 + u] = wb;
      if (u == TDT_U) GC4[b * TP + tp] = wb;
      if (u < TDT_U) {
        const float py = vt0 - lse - SIG;
        WY4[(b * TP + tp) * TDT_U + u] =
            make_float4(__expf(py + d0), __expf(py + d1),
                        __expf(py + d2), __expf(py + d3));
      }
      if (t < 4) {   // zero pads for tau<0 at tp=t
        const float4 z4 = make_float4(0.f, 0.f, 0.f, 0.f);
        WB4[(b * TP + t) * TDT_U1 + u] = z4;
        if (u == TDT_U) GC4[b * TP + t] = z4;
        if (u < TDT_U)  WY4[(b * TP + t) * TDT_U + u] = z4;
      }
      // publish this row (release: orders lane 0's stores device-wide)
      __hip_atomic_fetch_add(&cnt[t], 1u, __ATOMIC_RELEASE,
                             __HIP_MEMORY_SCOPE_AGENT);
    }
    return;
  }

  // ---------------- consumer: forward DP, one wave, b = blockIdx ---------
  if (threadIdx.x >= 64) return;
  const int b = blockIdx.x;
  const int l = threadIdx.x;
  const float4* WB4p = (const float4*)ws + (size_t)b * (TP * TDT_U1);
  const float4* WY4p = (const float4*)(ws + OFF_PYD) + (size_t)b * (TP * TDT_U);
  const float4* GC4p = (const float4*)(ws + OFF_GC) + (size_t)b * TP;

  // divergence-laundered zero: forces GC loads onto the VMEM vector pipe
  // (a provably-uniform address would become an out-of-order s_load; R4 trap)
  const int zdiv = __shfl((int)(threadIdx.x & 63), 0);

  unsigned fr = 0;  // production frontier: slices 0..fr-1 complete
#define GATE(NEED) do {                                                      \
    const int _need = (NEED);                                                \
    while ((int)fr <= _need) {                                               \
      if (__hip_atomic_load(&cnt[fr], __ATOMIC_ACQUIRE,                      \
                            __HIP_MEMORY_SCOPE_AGENT) >= ROWS_PER_SLICE)     \
        ++fr;                                                                \
      else __builtin_amdgcn_s_sleep(1);                                      \
    }                                                                        \
  } while (0)

  float4 B0,B1,B2,B3,B4,B5,B6,B7,B8,B9,B10,B11,B12,B13,B14;
  float4 Y0,Y1,Y2,Y3,Y4,Y5,Y6,Y7,Y8,Y9,Y10,Y11,Y12,Y13,Y14;
  float4 G0,G1,G2,G3,G4,G5,G6,G7,G8,G9,G10,G11,G12,G13,G14;

#define LOADSLOT(S, tpi) do {                \
    const int _tp = (tpi);                   \
    B##S = WB4p[_tp * TDT_U1 + l];           \
    Y##S = WY4p[_tp * TDT_U  + l];           \
    G##S = GC4p[_tp + zdiv];                 \
  } while (0)

  GATE(11);                      // slices 0..11 -> tp 1..15 ready (incl pads)
  LOADSLOT(1, 1);  LOADSLOT(2, 2);  LOADSLOT(3, 3);  LOADSLOT(4, 4);
  LOADSLOT(5, 5);  LOADSLOT(6, 6);  LOADSLOT(7, 7);  LOADSLOT(8, 8);
  LOADSLOT(9, 9);  LOADSLOT(10,10); LOADSLOT(11,11); LOADSLOT(12,12);
  LOADSLOT(13,13); LOADSLOT(14,14); LOADSLOT(0, 15);

  // A = exp(alpha + SHIFT*t - L); alpha0[0]=0 -> A=1 at u=0
  float a1 = (l == 0) ? 1.f : 0.f, a2 = 0.f, a3 = 0.f, a4 = 0.f;
  float c1 = 0.f, c2 = 0.f, c3 = 0.f, c4 = 0.f;
  float L = 0.f;

#define STEP(S0,S1,S2,S3, TPL) do {                                          \
    float ly0 = a1 * Y##S0.x, ly1 = a2 * Y##S1.y,                            \
          ly2 = a3 * Y##S2.z, ly3 = a4 * Y##S3.w;                            \
    float m0 = shup1(ly0), m1 = shup1(ly1),                                  \
          m2 = shup1(ly2), m3 = shup1(ly3);                                  \
    float cnew = c1*G##S0.x + c2*G##S1.y + c3*G##S2.z + c4*G##S3.w           \
               + ((ly0 + ly1) + (ly2 + ly3));                                \
    float anew = a1*B##S0.x + a2*B##S1.y + a3*B##S2.z + a4*B##S3.w           \
               + ((m0 + m1) + (m2 + m3));                                    \
    a4 = a3; a3 = a2; a2 = a1; a1 = anew;                                    \
    c4 = c3; c3 = c2; c2 = c1; c1 = cnew;                                    \
    LOADSLOT(S3, TPL);                                                       \
  } while (0)

  for (int tb = 1; tb < 256; tb += 15) {
    {
      const int need = (tb + 25 < 255) ? (tb + 25) : 255;  // covers tp<=tb+29
      GATE(need);
    }
    if (tb != 1) {
      // uniform renorm: scale by 1/max(two band probes); bookkeeping in L
      const float r1 = __shfl(a1, tb >> 3);
      const float r2 = __shfl(a1, tb >> 2);
      const float rl = fmaxf(r1, r2);
      const float sc = (rl > 1e-30f) ? (1.0f / rl) : 1.0f;
      L -= __logf(sc);
      a1 *= sc; a2 *= sc; a3 *= sc; a4 *= sc;
      c1 *= sc; c2 *= sc; c3 *= sc; c4 *= sc;
    }
    STEP(4,3,2,1,    tb + 15);
    STEP(5,4,3,2,    tb + 16);
    STEP(6,5,4,3,    tb + 17);
    STEP(7,6,5,4,    tb + 18);
    STEP(8,7,6,5,    tb + 19);
    STEP(9,8,7,6,    tb + 20);
    STEP(10,9,8,7,   tb + 21);
    STEP(11,10,9,8,  tb + 22);
    STEP(12,11,10,9, tb + 23);
    STEP(13,12,11,10,tb + 24);
    STEP(14,13,12,11,tb + 25);
    STEP(0,14,13,12, tb + 26);
    STEP(1,0,14,13,  tb + 27);
    STEP(2,1,0,14,   tb + 28);
    STEP(3,2,1,0,    tb + 29);
  }

  if (l == 63) {
    // ll = L - SHIFT*256 + log( sum_d C[256-d] * WG_d )
    const float4 g1 = GC4p[259 + zdiv];
    const float4 g2 = GC4p[258 + zdiv];
    const float4 g3 = GC4p[257 + zdiv];
    const float4 g4 = GC4p[256 + zdiv];
    const float sum = c1 * g1.x + c2 * g2.y + c3 * g3.z + c4 * g4.w;
    const float ll = L - SHIFT * 256.0f + __logf(sum);
    atomicAdd(out, ll * (-1.0f / TDT_B));
  }
#undef STEP
#undef LOADSLOT
#undef GATE
}

extern "C" void kernel_launch(void* const* d_in, const int* in_sizes, int n_in,
                              void* d_out, int out_size, void* d_ws, size_t ws_size,
                              hipStream_t stream)
{
  const float* la = (const float*)d_in[0];   // label_acts    (B,T,U+1,V+1) f32
  const float* da = (const float*)d_in[1];   // duration_acts (B,T,U+1,D)   f32
  const int*   tg = (const int*)d_in[2];     // targets       (B,U)         i32
  float* ws  = (float*)d_ws;
  float* out = (float*)d_out;

  unsigned* cnt = (unsigned*)(ws + OFF_CNT);
  k_zero<<<1, 256, 0, stream>>>(out, cnt);
  // 8 consumer blocks + 133120/4 producer blocks
  k_fused<<<8 + 33280, 256, 0, stream>>>(la, da, tg, ws, out);
}

// Round 9
// 100.473 us; speedup vs baseline: 23.4308x; 23.4308x over previous
//
#include <hip/hip_runtime.h>

// TDT loss, fixed shapes from setup_inputs():
#define TDT_B  8
#define TDT_T  256
#define TDT_U  64
#define TDT_U1 65
#define TDT_V1 513   // V+1, blank index = 512
#define TP     275   // 4 zero-pad slices + 256 + FIFO slack
#define SIG    0.05f
#define SHIFT  3.0f  // exponent shift PER TIME-STEP: duration-d weight carries SHIFT*d

// ws layout (floats):
//   WB: float4[B][TP][U1] = exp(lpb + ld_i - SIG + SHIFT*(i+1))
//   WY: float4[B][TP][U]  = exp(lpy + ld_i - SIG + SHIFT*(i+1))
#define OFF_PYD 572000                        // 8*275*65*4

// Kernel 1: per-(b,t,u) row log-softmax over 513 labels (wave per row, float2
// loads with odd-row alignment shim), duration log-softmax over 4, write
// EXP-DOMAIN W records with per-duration scale e^{SHIFT*d}. Zero pads tau<0.
// (Identical to the proven 47us R7 version.)
__global__ __launch_bounds__(256) void k_prep(
    const float* __restrict__ la, const float* __restrict__ da,
    const int* __restrict__ tgt, float* __restrict__ ws,
    float* __restrict__ out)
{
  if (blockIdx.x == 0 && threadIdx.x == 0) out[0] = 0.f;

  const int l = threadIdx.x & 63;
  const int r = (blockIdx.x << 2) + (threadIdx.x >> 6);   // row in [0, B*T*U1)
  const int u  = r % TDT_U1;
  const int bt = r / TDT_U1;
  const int t  = bt & (TDT_T - 1);
  const int b  = bt >> 8;

  const float* row = la + (size_t)r * TDT_V1;
  const int ofs = r & 1;                    // odd rows: shift by 1 for 8B align
  const float2* p2 = (const float2*)(row + ofs);
  float2 w[4];
#pragma unroll
  for (int k = 0; k < 4; ++k) w[k] = p2[l + (k << 6)];  // elems ofs+2l+128k+{0,1}
  const float extra = row[ofs ? 0 : 512];   // the one element outside the vec span

  float m = extra;
#pragma unroll
  for (int k = 0; k < 4; ++k) m = fmaxf(m, fmaxf(w[k].x, w[k].y));
#pragma unroll
  for (int off = 32; off; off >>= 1) m = fmaxf(m, __shfl_xor(m, off));
  float s = (l == 0) ? __expf(extra - m) : 0.f;
#pragma unroll
  for (int k = 0; k < 4; ++k) s += __expf(w[k].x - m) + __expf(w[k].y - m);
#pragma unroll
  for (int off = 32; off; off >>= 1) s += __shfl_xor(s, off);
  const float lse = m + __logf(s);

  // duration log-softmax (uniform per wave)
  const float4 dv = *(const float4*)(da + ((size_t)r << 2));
  const float m4 = fmaxf(fmaxf(dv.x, dv.y), fmaxf(dv.z, dv.w));
  const float l4 = m4 + __logf(__expf(dv.x - m4) + __expf(dv.y - m4) +
                               __expf(dv.z - m4) + __expf(dv.w - m4));
  // per-duration: ld_i - l4 + SHIFT*(i+1)  (scale-consistent exp domain)
  const float d0 = dv.x - l4 + SHIFT * 1.0f;
  const float d1 = dv.y - l4 + SHIFT * 2.0f;
  const float d2 = dv.z - l4 + SHIFT * 3.0f;
  const float d3 = dv.w - l4 + SHIFT * 4.0f;

  float4* WB4 = (float4*)ws;
  float4* WY4 = (float4*)(ws + OFF_PYD);

  const int tp = t + 4;
  // blank logit = elem 512: ofs==0 -> extra (owner lane 0); ofs==1 -> w[3].y (lane 63)
  const float xb = ofs ? w[3].y : extra;
  if (l == (ofs ? 63 : 0)) {
    const float pb = xb - lse - SIG;
    WB4[(b * TP + tp) * TDT_U1 + u] =
        make_float4(__expf(pb + d0), __expf(pb + d1), __expf(pb + d2), __expf(pb + d3));
  }

  // target gather (exactly one lane owns it); static indices only
  const int tg = (u < TDT_U) ? tgt[b * TDT_U + u] : -1;   // tg in [0,512)
  bool own = false; float vt = 0.f;
#pragma unroll
  for (int k = 0; k < 4; ++k) {
    const int base = ofs + ((l + (k << 6)) << 1);
    if (base == tg)     { vt = w[k].x; own = true; }
    if (base + 1 == tg) { vt = w[k].y; own = true; }
  }
  if (ofs && tg == 0 && l == 0) { vt = extra; own = true; }
  if (own) {
    const float py = vt - lse - SIG;
    WY4[(b * TP + tp) * TDT_U + u] =
        make_float4(__expf(py + d0), __expf(py + d1), __expf(py + d2), __expf(py + d3));
  }

  // zero pads for tau < 0 (slices tp = 0..3): exp(-inf) = 0
  if (t < 4 && l == 0) {
    const float4 z4 = make_float4(0.f, 0.f, 0.f, 0.f);
    WB4[(b * TP + t) * TDT_U1 + u] = z4;
    if (u < TDT_U) WY4[(b * TP + t) * TDT_U + u] = z4;
  }
}

// DPP wave_shr:1 (ctrl 0x138), bound_ctrl=1 -> lane 0 reads 0. VALU-pipe
// lane shift replacing ds_bpermute on the serial t-chain.
__device__ __forceinline__ float shup1(float x) {
  const int r = __builtin_amdgcn_update_dpp(
      0, __float_as_int(x), 0x138, 0xf, 0xf, true);
  return __int_as_float(r);
}

// Loader-wave helper: fill group j (slices 15j+1 .. 15j+15) of the LDS ring.
// Waves 1..3 each own 5 slices (interleaved). Ring = 30 slices, parity halves.
// Slice s -> ring slot (s-1) % 30; group j occupies slots 15*(j&1) + 0..14.
__device__ __forceinline__ void fill_group(
    const float4* __restrict__ WB4p, const float4* __restrict__ WY4p,
    float4* ring, int j, int wv, int l)
{
  const int sb = 15 * j + wv;               // this wave's first slice in group
  const int rb = 15 * (j & 1) + (wv - 1);   // its first ring slot
#pragma unroll
  for (int k = 0; k < 5; ++k) {
    const int s    = sb + 3 * k;
    const int slot = rb + 3 * k;
    const float4* sB = WB4p + (size_t)s * TDT_U1;
    const float4* sY = WY4p + (size_t)s * TDT_U;
    const float4 vb = sB[l];
    const float4 vy = sY[l];
    ring[slot * 130 + l]      = vb;          // B[u=l]
    ring[slot * 130 + 65 + l] = vy;          // Y[u=l]
    if (l == 0) ring[slot * 130 + 64] = sB[64];   // B[u=64] tail
  }
}

// Kernel 2: forward DP, exp domain. 8 blocks (one per b) x 4 waves.
// Wave 0: the serial chain (register FIFO fed from LDS, in-order lgkmcnt,
// ~120cyc latency -> fully covered). Waves 1-3: stream W slices from global
// into a 30-slice LDS double-buffer ring, one group (15 slices) per
// iteration, __syncthreads-pipelined: chain reads parity (i+1)&1 while
// loaders fill parity i&1. Global latency lives entirely on loader waves.
__global__ __launch_bounds__(256, 1) void k_dp(
    const float* __restrict__ ws, float* __restrict__ out)
{
  const int b  = blockIdx.x;
  const int wv = threadIdx.x >> 6;
  const int l  = threadIdx.x & 63;
  const float4* WB4p = (const float4*)ws + (size_t)b * (TP * TDT_U1);
  const float4* WY4p = (const float4*)(ws + OFF_PYD) + (size_t)b * (TP * TDT_U);

  __shared__ float4 ring_s[30 * 130];       // 62.4 KB: 30 slices x (65 B + 64 Y + pad)
  float4* ring = ring_s;

  // prologue: loaders fill group 0 (slices 1..15)
  if (wv != 0) fill_group(WB4p, WY4p, ring, 0, wv, l);
  __syncthreads();

  float4 B0,B1,B2,B3,B4,B5,B6,B7,B8,B9,B10,B11,B12,B13,B14;
  float4 Y0,Y1,Y2,Y3,Y4,Y5,Y6,Y7,Y8,Y9,Y10,Y11,Y12,Y13,Y14;
  float4 G0,G1,G2,G3,G4,G5,G6,G7,G8,G9,G10,G11,G12,G13,G14;
  float a1 = 0.f, a2 = 0.f, a3 = 0.f, a4 = 0.f;
  float c1 = 0.f, c2 = 0.f, c3 = 0.f, c4 = 0.f;
  float L = 0.f;

#define LOADSLOT(S, RS) do {                 \
    const int _rb4 = (RS) * 130;             \
    B##S = ring[_rb4 + l];                   \
    Y##S = ring[_rb4 + 65 + l];              \
    G##S = ring[_rb4 + 64];                  \
  } while (0)

  if (wv == 0) {
    // preload group 0: slices 1..15 -> ring slots 0..14, FIFO slot s%15
    LOADSLOT(1, 0);  LOADSLOT(2, 1);  LOADSLOT(3, 2);  LOADSLOT(4, 3);
    LOADSLOT(5, 4);  LOADSLOT(6, 5);  LOADSLOT(7, 6);  LOADSLOT(8, 7);
    LOADSLOT(9, 8);  LOADSLOT(10,9);  LOADSLOT(11,10); LOADSLOT(12,11);
    LOADSLOT(13,12); LOADSLOT(14,13); LOADSLOT(0, 14);
    a1 = (l == 0) ? 1.f : 0.f;               // A = exp(alpha + SHIFT*t - L)
  }

#define STEP(S0,S1,S2,S3, RSL) do {                                          \
    float ly0 = a1 * Y##S0.x, ly1 = a2 * Y##S1.y,                            \
          ly2 = a3 * Y##S2.z, ly3 = a4 * Y##S3.w;                            \
    float m0 = shup1(ly0), m1 = shup1(ly1),                                  \
          m2 = shup1(ly2), m3 = shup1(ly3);                                  \
    float cnew = c1*G##S0.x + c2*G##S1.y + c3*G##S2.z + c4*G##S3.w           \
               + ((ly0 + ly1) + (ly2 + ly3));                                \
    float anew = a1*B##S0.x + a2*B##S1.y + a3*B##S2.z + a4*B##S3.w           \
               + ((m0 + m1) + (m2 + m3));                                    \
    a4 = a3; a3 = a2; a2 = a1; a1 = anew;                                    \
    c4 = c3; c3 = c2; c2 = c1; c1 = cnew;                                    \
    LOADSLOT(S3, RSL);                                                       \
  } while (0)

  for (int i = 0, tb = 1; i < 17; ++i, tb += 15) {
    // loaders: fill group i+1 (groups 1..17); chain preload/compute overlaps
    if (wv != 0) fill_group(WB4p, WY4p, ring, i + 1, wv, l);
    __syncthreads();
    if (wv == 0) {
      const int rb = 15 * ((i + 1) & 1);    // ring slots of slices tb+15..tb+29
      if (i) {
        // uniform renorm: scale by 1/max(two band probes); bookkeeping in L
        const float r1 = __shfl(a1, tb >> 3);
        const float r2 = __shfl(a1, tb >> 2);
        const float rl = fmaxf(r1, r2);
        const float sc = (rl > 1e-30f) ? (1.0f / rl) : 1.0f;
        L -= __logf(sc);
        a1 *= sc; a2 *= sc; a3 *= sc; a4 *= sc;
        c1 *= sc; c2 *= sc; c3 *= sc; c4 *= sc;
      }
      STEP(4,3,2,1,    rb + 0);
      STEP(5,4,3,2,    rb + 1);
      STEP(6,5,4,3,    rb + 2);
      STEP(7,6,5,4,    rb + 3);
      STEP(8,7,6,5,    rb + 4);
      STEP(9,8,7,6,    rb + 5);
      STEP(10,9,8,7,   rb + 6);
      STEP(11,10,9,8,  rb + 7);
      STEP(12,11,10,9, rb + 8);
      STEP(13,12,11,10,rb + 9);
      STEP(14,13,12,11,rb + 10);
      STEP(0,14,13,12, rb + 11);
      STEP(1,0,14,13,  rb + 12);
      STEP(2,1,0,14,   rb + 13);
      STEP(3,2,1,0,    rb + 14);
    }
  }

  if (wv == 0 && l == 63) {
    // ll = L - SHIFT*256 + log( sum_d C[256-d] * WG_d )
    // slice s -> ring slot (s-1)%30: 259->18, 258->17, 257->16, 256->15
    // (group 17 = slices 256..270 occupies slots 15..29; no later overwrite)
    const float sum = c1 * ring[18 * 130 + 64].x
                    + c2 * ring[17 * 130 + 64].y
                    + c3 * ring[16 * 130 + 64].z
                    + c4 * ring[15 * 130 + 64].w;
    const float ll = L - SHIFT * 256.0f + __logf(sum);
    atomicAdd(out, ll * (-1.0f / TDT_B));
  }
#undef STEP
#undef LOADSLOT
}

extern "C" void kernel_launch(void* const* d_in, const int* in_sizes, int n_in,
                              void* d_out, int out_size, void* d_ws, size_t ws_size,
                              hipStream_t stream)
{
  const float* la = (const float*)d_in[0];   // label_acts    (B,T,U+1,V+1) f32
  const float* da = (const float*)d_in[1];   // duration_acts (B,T,U+1,D)   f32
  const int*   tg = (const int*)d_in[2];     // targets       (B,U)         i32
  float* ws  = (float*)d_ws;
  float* out = (float*)d_out;

  const int rows = TDT_B * TDT_T * TDT_U1;   // 133120
  k_prep<<<rows / 4, 256, 0, stream>>>(la, da, tg, ws, out);
  k_dp  <<<TDT_B, 256, 0, stream>>>(ws, out);
}